// Round 15
// baseline (25.129 us; speedup 1.0000x reference)
//
#include <hip/hip_runtime.h>
#include <hip/hip_bf16.h>
#include <stdint.h>

// LogLinearCDE: out = softmax(W_out @ (y0 * prod_l flows[l]) + b_out)
// flows[l,h] = 1 + sum_c logsigs[l,c]*vf_A[c,h];  y0 = W_in@x0 + b_in
// R15: TWO kernels, no fences/atomics/counters.
// (1) partial: grid (64 colgroups x 8 rowsplits). Block = 64 cols x 2048 rows,
//     16 iters of 128 rows via 32x32x16_f16 MFMA (main + k16 cleanup), f16
//     single precision (R14-validated, absmax ~6e-5). y0 folded in at rq==0.
//     Output ws_pp[8][4096] = 128 KB.
// (2) tail: ONE 1024-thread block: 8-way product per h, W_out logits with
//     fixed-order reduction, softmax. ~288 KB coalesced reads.

#define LSTEPS 16384
#define HID    4096
#define CC     17
#define NLAB   10
#define CPBLK  64               // cols per partial block
#define NCG    (HID/CPBLK)      // 64 col groups
#define RQ     8                // row splits
#define RPB    (LSTEPS/RQ)      // 2048 rows per block
#define ITERS  (RPB/128)        // 16

typedef __attribute__((ext_vector_type(8)))  _Float16 half8;
typedef __attribute__((ext_vector_type(8)))  short short8;
typedef __attribute__((ext_vector_type(16))) float f32x16;

static __device__ __forceinline__ unsigned short f2h(float x) {
  _Float16 h = (_Float16)x;
  return *reinterpret_cast<unsigned short*>(&h);
}
static __device__ __forceinline__ uint32_t pk(unsigned short lo, unsigned short hi) {
  return (uint32_t)lo | ((uint32_t)hi << 16);
}
static __device__ __forceinline__ half8 frag_from_word(uint32_t w) {
  short8 s = {};
  s[0] = (short)(w & 0xffffu);
  s[1] = (short)(w >> 16);
  return __builtin_bit_cast(half8, s);
}

__global__ __launch_bounds__(256, 2) void partial_kernel(
    const float* __restrict__ logsigs, const float* __restrict__ vfA,
    const float* __restrict__ Win, const float* __restrict__ bin,
    const float* __restrict__ x0, float* __restrict__ ws_pp) {
  const int cg = blockIdx.x;    // 0..63
  const int rq = blockIdx.y;    // 0..7
  const int tid = threadIdx.x;
  const int gc0 = cg * CPBLK;

  __shared__ __align__(16) uint32_t sA[128][8];   // k0-15 f16 pairs
  __shared__ uint32_t sA4[128];                   // k16
  __shared__ __align__(16) uint32_t sB[2][CPBLK][4];
  __shared__ uint32_t sB4[CPBLK];
  __shared__ float sw[4][CPBLK];

  // ---- stage B once: thread t<64 -> col t (k-loop coalesces across lanes)
  if (tid < CPBLK) {
    const int gc = gc0 + tid;
    float v[CC];
    #pragma unroll
    for (int k = 0; k < CC; ++k) v[k] = vfA[(size_t)k*HID + gc];
    #pragma unroll
    for (int j = 0; j < 4; ++j) {
      sB[0][tid][j] = pk(f2h(v[2*j]),   f2h(v[2*j+1]));   // k0-7
      sB[1][tid][j] = pk(f2h(v[8+2*j]), f2h(v[9+2*j]));   // k8-15
    }
    sB4[tid] = pk(f2h(v[16]), 0);
  }

  const int lane = tid & 63, wv = tid >> 6;
  const int cl = lane & 31, kh = lane >> 5;

  float p0 = 1.0f, p1 = 1.0f;
  const float* __restrict__ abase = logsigs + (size_t)rq*RPB*CC;

  for (int it = 0; it < ITERS; ++it) {
    __syncthreads();              // prev-iter readers done / B visible (it=0)
    // ---- stage A: 128 rows, 2 threads per row
    {
      const int r = tid >> 1, hf = tid & 1;
      const float* __restrict__ row = abase + (size_t)(it*128 + r)*CC;
      if (hf == 0) {
        #pragma unroll
        for (int j = 0; j < 4; ++j)
          sA[r][j] = pk(f2h(row[2*j]), f2h(row[2*j+1]));
      } else {
        #pragma unroll
        for (int j = 0; j < 4; ++j)
          sA[r][4+j] = pk(f2h(row[8+2*j]), f2h(row[9+2*j]));
        sA4[r] = pk(f2h(row[16]), 0);
      }
    }
    __syncthreads();
    // ---- compute: wave wv = row-tile wv; 2 col-tiles per wave
    const int r = wv*32 + cl;
    const half8 Am = __builtin_bit_cast(half8,
                       *reinterpret_cast<const short8*>(&sA[r][kh*4]));
    const half8 A4 = frag_from_word((kh == 0) ? sA4[r] : 0u);

    const half8 Bm0 = __builtin_bit_cast(half8,
                        *reinterpret_cast<const short8*>(&sB[kh][cl][0]));
    const half8 Bm1 = __builtin_bit_cast(half8,
                        *reinterpret_cast<const short8*>(&sB[kh][32+cl][0]));
    const half8 B40 = frag_from_word((kh == 0) ? sB4[cl] : 0u);
    const half8 B41 = frag_from_word((kh == 0) ? sB4[32+cl] : 0u);

    f32x16 a0 = {}, a1 = {};
    a0 = __builtin_amdgcn_mfma_f32_32x32x16_f16(Am, Bm0, a0, 0, 0, 0);
    a0 = __builtin_amdgcn_mfma_f32_32x32x16_f16(A4, B40, a0, 0, 0, 0);
    a1 = __builtin_amdgcn_mfma_f32_32x32x16_f16(Am, Bm1, a1, 0, 0, 0);
    a1 = __builtin_amdgcn_mfma_f32_32x32x16_f16(A4, B41, a1, 0, 0, 0);
    #pragma unroll
    for (int i = 0; i < 16; ++i) {
      p0 *= (1.0f + a0[i]);
      p1 *= (1.0f + a1[i]);
    }
  }
  // partner lane (^32) holds the other 16 rows of this row-tile
  p0 *= __shfl_xor(p0, 32, 64);
  p1 *= __shfl_xor(p1, 32, 64);
  __syncthreads();
  if (kh == 0) { sw[wv][cl] = p0; sw[wv][32+cl] = p1; }
  __syncthreads();
  if (tid < CPBLK) {
    float P = (sw[0][tid]*sw[1][tid]) * (sw[2][tid]*sw[3][tid]);
    const int gc = gc0 + tid;
    if (rq == 0) {              // fold y0 = W_in@x0 + b_in into split 0
      const float4* __restrict__ wrow =
          reinterpret_cast<const float4*>(Win + (size_t)gc*16);
      float y = bin[gc];
      #pragma unroll
      for (int q = 0; q < 4; ++q) {
        float4 w = wrow[q];
        y = fmaf(w.x, x0[4*q+0], y);
        y = fmaf(w.y, x0[4*q+1], y);
        y = fmaf(w.z, x0[4*q+2], y);
        y = fmaf(w.w, x0[4*q+3], y);
      }
      P *= y;
    }
    ws_pp[(size_t)rq*HID + gc] = P;
  }
}

// tail: ONE block, 1024 threads. sy = prod_rq ws_pp; logits; softmax.
__global__ __launch_bounds__(1024) void tail_kernel(
    const float* __restrict__ ws_pp, const float* __restrict__ Wout,
    const float* __restrict__ bout, float* __restrict__ out) {
  const int tid = threadIdx.x;
  __shared__ float ssy[HID];              // 16 KB
  __shared__ float sred[16][NLAB];
  __shared__ float slog[NLAB];

  #pragma unroll
  for (int rep = 0; rep < HID/1024; ++rep) {     // 4
    const int h = rep*1024 + tid;
    float p = 1.0f;
    #pragma unroll
    for (int r = 0; r < RQ; ++r) p *= ws_pp[(size_t)r*HID + h];
    ssy[h] = p;                                  // = y0[h] * P[h]
  }
  __syncthreads();

  float acc[NLAB];
  #pragma unroll
  for (int j = 0; j < NLAB; ++j) acc[j] = 0.0f;
  #pragma unroll
  for (int rep = 0; rep < HID/1024; ++rep) {
    const int h = rep*1024 + tid;
    const float y = ssy[h];
    #pragma unroll
    for (int j = 0; j < NLAB; ++j)
      acc[j] = fmaf(Wout[(size_t)j*HID + h], y, acc[j]);
  }
  const int wv = tid >> 6, lane = tid & 63;
  #pragma unroll
  for (int j = 0; j < NLAB; ++j) {
    #pragma unroll
    for (int off = 1; off < 64; off <<= 1)
      acc[j] += __shfl_xor(acc[j], off, 64);
  }
  if (lane == 0) {
    #pragma unroll
    for (int j = 0; j < NLAB; ++j) sred[wv][j] = acc[j];
  }
  __syncthreads();
  if (tid < NLAB) {
    float s = bout[tid];
    #pragma unroll
    for (int w = 0; w < 16; ++w) s += sred[w][tid];
    slog[tid] = s;
  }
  __syncthreads();
  if (tid == 0) {
    float m = slog[0];
    #pragma unroll
    for (int j = 1; j < NLAB; ++j) m = fmaxf(m, slog[j]);
    float ssum = 0.0f;
    float e[NLAB];
    #pragma unroll
    for (int j = 0; j < NLAB; ++j) { e[j] = __expf(slog[j] - m); ssum += e[j]; }
    const float inv = 1.0f / ssum;
    #pragma unroll
    for (int j = 0; j < NLAB; ++j) out[j] = e[j] * inv;
  }
}

extern "C" void kernel_launch(void* const* d_in, const int* in_sizes, int n_in,
                              void* d_out, int out_size, void* d_ws, size_t ws_size,
                              hipStream_t stream) {
  // inputs: 0=ts (unused), 1=logsigs (L,C), 2=x0 (D), 3=W_in (H,D), 4=b_in (H),
  //         5=vf_A (C,H), 6=W_out (10,H), 7=b_out (10)
  const float* logsigs = (const float*)d_in[1];
  const float* x0      = (const float*)d_in[2];
  const float* Win     = (const float*)d_in[3];
  const float* bin     = (const float*)d_in[4];
  const float* vfA     = (const float*)d_in[5];
  const float* Wout    = (const float*)d_in[6];
  const float* bout    = (const float*)d_in[7];
  float* out = (float*)d_out;

  float* ws_pp = (float*)d_ws;     // RQ * HID f32 = 128 KB

  partial_kernel<<<dim3(NCG, RQ), 256, 0, stream>>>(logsigs, vfA, Win, bin, x0, ws_pp);
  tail_kernel<<<1, 1024, 0, stream>>>(ws_pp, Wout, bout, out);
}

// Round 17
// 17.582 us; speedup vs baseline: 1.4292x; 1.4292x over previous
//
#include <hip/hip_runtime.h>
#include <hip/hip_bf16.h>
#include <stdint.h>

// LogLinearCDE: out = softmax(W_out @ (y0 * prod_l flows[l]) + b_out)
// flows[l,h] = 1 + sum_c logsigs[l,c]*vf_A[c,h];  y0 = W_in@x0 + b_in
// R17: TWO kernels, race-immune partial (single barrier, read-only LDS).
// partial: grid (16 colgroups x 16 rowsplits), 512 thr. Stage 1024 rows of A
// (36KB) + 256 cols of B (9KB) once -> ONE __syncthreads -> 32 row-tiles x
// 2 MFMAs (f16 main + k16 cleanup), fmaf product epilogue, y0 fold at rq==0.
// tail: ONE 1024-thread block, float4-resident, fixed-order logit reduction.

#define LSTEPS 16384
#define HID    4096
#define CC     17
#define NLAB   10
#define COLS   256              // cols per partial block
#define NCB    (HID/COLS)       // 16
#define RQ     16               // row splits
#define RPB    (LSTEPS/RQ)      // 1024 rows per block

typedef __attribute__((ext_vector_type(8)))  _Float16 half8;
typedef __attribute__((ext_vector_type(8)))  short short8;
typedef __attribute__((ext_vector_type(16))) float f32x16;

static __device__ __forceinline__ unsigned short f2h(float x) {
  _Float16 h = (_Float16)x;
  return *reinterpret_cast<unsigned short*>(&h);
}
static __device__ __forceinline__ uint32_t pk(unsigned short lo, unsigned short hi) {
  return (uint32_t)lo | ((uint32_t)hi << 16);
}
static __device__ __forceinline__ half8 frag_from_word(uint32_t w) {
  short8 s = {};
  s[0] = (short)(w & 0xffffu);
  s[1] = (short)(w >> 16);
  return __builtin_bit_cast(half8, s);
}

__global__ __launch_bounds__(512, 2) void partial_kernel(
    const float* __restrict__ logsigs, const float* __restrict__ vfA,
    const float* __restrict__ Win, const float* __restrict__ bin,
    const float* __restrict__ x0, float* __restrict__ ws_pp) {
  const int cb = blockIdx.x;    // 0..15 col group (256 cols)
  const int rq = blockIdx.y;    // 0..15 row split (1024 rows)
  const int tid = threadIdx.x;  // 512 threads

  __shared__ __align__(16) uint32_t sA[RPB][8];    // 32 KB  (k0-15 f16 pairs)
  __shared__ uint32_t sA4[RPB];                    //  4 KB  (k16)
  __shared__ __align__(16) uint32_t sB[2][COLS][4];//  8 KB
  __shared__ uint32_t sB4[COLS];                   //  1 KB

  // ---- stage B (tid < 256): col tid; k-loop coalesces across lanes
  if (tid < COLS) {
    const int gc = cb*COLS + tid;
    float v[CC];
    #pragma unroll
    for (int k = 0; k < CC; ++k) v[k] = vfA[(size_t)k*HID + gc];
    uint32_t w0[4], w1[4];
    #pragma unroll
    for (int j = 0; j < 4; ++j) {
      w0[j] = pk(f2h(v[2*j]),   f2h(v[2*j+1]));   // k0-7
      w1[j] = pk(f2h(v[8+2*j]), f2h(v[9+2*j]));   // k8-15
    }
    *reinterpret_cast<uint4*>(&sB[0][tid][0]) = make_uint4(w0[0],w0[1],w0[2],w0[3]);
    *reinterpret_cast<uint4*>(&sB[1][tid][0]) = make_uint4(w1[0],w1[1],w1[2],w1[3]);
    sB4[tid] = pk(f2h(v[16]), 0);
  }

  // ---- stage A: 1024 rows x 2 half-rows = 2048 tasks, 4 rounds of 512
  {
    const float* __restrict__ abase = logsigs + (size_t)rq*RPB*CC;
    #pragma unroll
    for (int rd = 0; rd < 4; ++rd) {
      const int e = rd*512 + tid;
      const int r = e >> 1, hf = e & 1;
      const float* __restrict__ row = abase + (size_t)r*CC + hf*8;
      uint32_t w[4];
      #pragma unroll
      for (int j = 0; j < 4; ++j) w[j] = pk(f2h(row[2*j]), f2h(row[2*j+1]));
      *reinterpret_cast<uint4*>(&sA[r][hf*4]) = make_uint4(w[0],w[1],w[2],w[3]);
      if (hf) sA4[r] = pk(f2h(row[8]), 0);
    }
  }
  __syncthreads();      // the ONLY barrier: LDS is read-only from here on

  const int lane = tid & 63, wv = tid >> 6;   // 8 waves
  const int cl = lane & 31, kh = lane >> 5;
  const int c = wv*32 + cl;                   // col within block

  const half8 Bm = __builtin_bit_cast(half8,
                     *reinterpret_cast<const short8*>(&sB[kh][c][0]));
  const half8 B4 = frag_from_word((kh == 0) ? sB4[c] : 0u);

  float p = 1.0f;
  #pragma unroll 4
  for (int it = 0; it < RPB/32; ++it) {       // 32 row-tiles
    const int rr = it*32 + cl;
    const half8 Am = __builtin_bit_cast(half8,
                       *reinterpret_cast<const short8*>(&sA[rr][kh*4]));
    const half8 A4 = frag_from_word((kh == 0) ? sA4[rr] : 0u);
    f32x16 a = {};
    a = __builtin_amdgcn_mfma_f32_32x32x16_f16(Am, Bm, a, 0, 0, 0);
    a = __builtin_amdgcn_mfma_f32_32x32x16_f16(A4, B4, a, 0, 0, 0);
    #pragma unroll
    for (int i = 0; i < 16; ++i) p = fmaf(a[i], p, p);   // p *= (1 + a[i])
  }
  // partner lane (^32) holds the other 16 rows of each 32-row tile
  p *= __shfl_xor(p, 32, 64);

  if (kh == 0) {
    const int gc = cb*COLS + c;
    float P = p;
    if (rq == 0) {              // fold y0 = W_in@x0 + b_in
      const float4* __restrict__ wrow =
          reinterpret_cast<const float4*>(Win + (size_t)gc*16);
      float y = bin[gc];
      #pragma unroll
      for (int q = 0; q < 4; ++q) {
        float4 w = wrow[q];
        y = fmaf(w.x, x0[4*q+0], y);
        y = fmaf(w.y, x0[4*q+1], y);
        y = fmaf(w.z, x0[4*q+2], y);
        y = fmaf(w.w, x0[4*q+3], y);
      }
      P *= y;
    }
    ws_pp[(size_t)rq*HID + gc] = P;
  }
}

// tail: ONE block, 1024 threads; thread owns 4 h (float4). No LDS staging.
__global__ __launch_bounds__(1024) void tail_kernel(
    const float* __restrict__ ws_pp, const float* __restrict__ Wout,
    const float* __restrict__ bout, float* __restrict__ out) {
  const int tid = threadIdx.x;
  __shared__ float sred[16][NLAB];
  __shared__ float slog[NLAB];

  const float4* __restrict__ pp4 = reinterpret_cast<const float4*>(ws_pp);
  float4 p = make_float4(1.0f, 1.0f, 1.0f, 1.0f);
  #pragma unroll
  for (int r = 0; r < RQ; ++r) {
    float4 v = pp4[(size_t)r*(HID/4) + tid];
    p.x *= v.x; p.y *= v.y; p.z *= v.z; p.w *= v.w;
  }

  const float4* __restrict__ wo4 = reinterpret_cast<const float4*>(Wout);
  float acc[NLAB];
  #pragma unroll
  for (int j = 0; j < NLAB; ++j) {
    float4 w = wo4[(size_t)j*(HID/4) + tid];
    acc[j] = w.x*p.x + w.y*p.y + w.z*p.z + w.w*p.w;
  }

  const int wv = tid >> 6, lane = tid & 63;
  #pragma unroll
  for (int j = 0; j < NLAB; ++j) {
    #pragma unroll
    for (int off = 1; off < 64; off <<= 1)
      acc[j] += __shfl_xor(acc[j], off, 64);
  }
  if (lane == 0) {
    #pragma unroll
    for (int j = 0; j < NLAB; ++j) sred[wv][j] = acc[j];
  }
  __syncthreads();
  if (tid < NLAB) {
    float s = bout[tid];
    #pragma unroll
    for (int w = 0; w < 16; ++w) s += sred[w][tid];
    slog[tid] = s;
  }
  __syncthreads();
  if (tid == 0) {
    float m = slog[0];
    #pragma unroll
    for (int j = 1; j < NLAB; ++j) m = fmaxf(m, slog[j]);
    float ssum = 0.0f;
    float e[NLAB];
    #pragma unroll
    for (int j = 0; j < NLAB; ++j) { e[j] = __expf(slog[j] - m); ssum += e[j]; }
    const float inv = 1.0f / ssum;
    #pragma unroll
    for (int j = 0; j < NLAB; ++j) out[j] = e[j] * inv;
  }
}

extern "C" void kernel_launch(void* const* d_in, const int* in_sizes, int n_in,
                              void* d_out, int out_size, void* d_ws, size_t ws_size,
                              hipStream_t stream) {
  // inputs: 0=ts (unused), 1=logsigs (L,C), 2=x0 (D), 3=W_in (H,D), 4=b_in (H),
  //         5=vf_A (C,H), 6=W_out (10,H), 7=b_out (10)
  const float* logsigs = (const float*)d_in[1];
  const float* x0      = (const float*)d_in[2];
  const float* Win     = (const float*)d_in[3];
  const float* bin     = (const float*)d_in[4];
  const float* vfA     = (const float*)d_in[5];
  const float* Wout    = (const float*)d_in[6];
  const float* bout    = (const float*)d_in[7];
  float* out = (float*)d_out;

  float* ws_pp = (float*)d_ws;     // RQ * HID f32 = 256 KB

  partial_kernel<<<dim3(NCB, RQ), 512, 0, stream>>>(logsigs, vfA, Win, bin, x0, ws_pp);
  tail_kernel<<<1, 1024, 0, stream>>>(ws_pp, Wout, bout, out);
}